// Round 5
// baseline (411.459 us; speedup 1.0000x reference)
//
#include <hip/hip_runtime.h>
#include <hip/hip_bf16.h>
#include <math.h>

#define L 32768
#define C 256
#define QD 512
#define SCALE (1.0f/16.0f)

typedef __hip_bfloat16 bf16;
typedef short v8s __attribute__((ext_vector_type(8)));
typedef short v4s __attribute__((ext_vector_type(4)));
typedef float v4f __attribute__((ext_vector_type(4)));

__device__ __forceinline__ void ldst16(void* lds, const void* g) {
    __builtin_amdgcn_global_load_lds(
        (const __attribute__((address_space(1))) unsigned int*)g,
        (__attribute__((address_space(3))) unsigned int*)lds, 16, 0, 0);
}
__device__ __forceinline__ short bfbits(float x) {
    bf16 h = __float2bfloat16(x);
    return *reinterpret_cast<short*>(&h);
}

// ---------------------------------------------------------------------------
// prep: pack Wq/Wk/Wv -> Wall bf16 [768][512]; Wo -> Wob bf16 [512][256];
// biases -> ball fp32 [768].
// ---------------------------------------------------------------------------
__global__ __launch_bounds__(256) void prep(
    const float* __restrict__ Wq, const float* __restrict__ Wk,
    const float* __restrict__ Wv, const float* __restrict__ bq,
    const float* __restrict__ bk, const float* __restrict__ bv,
    const float* __restrict__ Wo,
    bf16* __restrict__ Wall, bf16* __restrict__ Wob, float* __restrict__ ball)
{
    int i = blockIdx.x * 256 + threadIdx.x;
    if (i < 768*512) {
        int row = i >> 9, idx = i & 511;
        const float* src = row < 256 ? Wq : row < 512 ? Wk : Wv;
        Wall[i] = __float2bfloat16(src[(row & 255) * 512 + idx]);
    } else if (i < 768*512 + 512*256) {
        int j = i - 768*512;
        Wob[j] = __float2bfloat16(Wo[j]);
    } else if (i < 768*512 + 512*256 + 768) {
        int j = i - 768*512 - 512*256;
        ball[j] = j < 256 ? bq[j] : j < 512 ? bk[j - 256] : bv[j - 512];
    }
}

// ---------------------------------------------------------------------------
// convt: x1 fp32 [512][L] -> x1T bf16 [L][512], 64x64 tiles via LDS.
// ---------------------------------------------------------------------------
__global__ __launch_bounds__(256) void convt(
    const float* __restrict__ x, short* __restrict__ xT)
{
    __shared__ short st[64*72];
    const int t = threadIdx.x;
    const int l0 = blockIdx.x * 64, c0 = blockIdx.y * 64;
    #pragma unroll
    for (int i = 0; i < 2; i++) {
        int v = i*256 + t;
        int c = v >> 3, l8 = (v & 7) << 3;
        const float* p = x + (size_t)(c0 + c) * L + l0 + l8;
        float4 f0 = *(const float4*)p;
        float4 f1 = *(const float4*)(p + 4);
        bf16* stb = (bf16*)st;
        stb[(l8+0)*72 + c] = __float2bfloat16(f0.x);
        stb[(l8+1)*72 + c] = __float2bfloat16(f0.y);
        stb[(l8+2)*72 + c] = __float2bfloat16(f0.z);
        stb[(l8+3)*72 + c] = __float2bfloat16(f0.w);
        stb[(l8+4)*72 + c] = __float2bfloat16(f1.x);
        stb[(l8+5)*72 + c] = __float2bfloat16(f1.y);
        stb[(l8+6)*72 + c] = __float2bfloat16(f1.z);
        stb[(l8+7)*72 + c] = __float2bfloat16(f1.w);
    }
    __syncthreads();
    #pragma unroll
    for (int i = 0; i < 2; i++) {
        int v = i*256 + t;
        int l = v >> 3, c8 = (v & 7) << 3;
        *(v8s*)(xT + (size_t)(l0 + l) * QD + c0 + c8) = *(const v8s*)&st[l*72 + c8];
    }
}

// ---------------------------------------------------------------------------
// Fused QKV GEMM (m97-style): Y[768][L] = Wall[768][512] . x1T[L][512]^T.
// ---------------------------------------------------------------------------
__global__ __launch_bounds__(256) void qkv_gemm(
    const bf16* __restrict__ A, const bf16* __restrict__ B,
    const float* __restrict__ ball,
    bf16* __restrict__ qT, bf16* __restrict__ kT, bf16* __restrict__ vB)
{
    __shared__ short sA[128*32];
    __shared__ short sB[128*32];
    __shared__ short sE[128*136];

    const int t    = threadIdx.x;
    const int lane = t & 63;
    const int w    = t >> 6;
    const int wm   = w & 1, wn = w >> 1;
    const int col  = lane & 15, quad = lane >> 4;
    const int n0   = blockIdx.x * 128;
    const int my   = blockIdx.y;
    const int m0   = my * 128;

    v4f acc[4][4];
    #pragma unroll
    for (int i = 0; i < 4; i++)
        #pragma unroll
        for (int j = 0; j < 4; j++) acc[i][j] = (v4f){0.f,0.f,0.f,0.f};

    for (int k0 = 0; k0 < QD; k0 += 32) {
        #pragma unroll
        for (int j = 0; j < 2; j++) {
            int idx = j*256 + t;
            int m = idx >> 2, k8 = (idx & 3) << 3;
            ldst16(&sA[idx*8], A + (size_t)(m0 + m) * QD + k0 + k8);
        }
        #pragma unroll
        for (int j = 0; j < 2; j++) {
            int idx = j*256 + t;
            int n = idx >> 2, k8 = (idx & 3) << 3;
            ldst16(&sB[idx*8], B + (size_t)(n0 + n) * QD + k0 + k8);
        }
        __syncthreads();
        v8s af[4], bf[4];
        #pragma unroll
        for (int mt = 0; mt < 4; mt++)
            af[mt] = *(const v8s*)&sA[(wm*64 + mt*16 + col)*32 + quad*8];
        #pragma unroll
        for (int nt = 0; nt < 4; nt++)
            bf[nt] = *(const v8s*)&sB[(wn*64 + nt*16 + col)*32 + quad*8];
        #pragma unroll
        for (int mt = 0; mt < 4; mt++)
            #pragma unroll
            for (int nt = 0; nt < 4; nt++)
                acc[mt][nt] = __builtin_amdgcn_mfma_f32_16x16x32_bf16(af[mt], bf[nt], acc[mt][nt], 0, 0, 0);
        __syncthreads();
    }

    float bias_v[4][4];
    #pragma unroll
    for (int mt = 0; mt < 4; mt++)
        #pragma unroll
        for (int r = 0; r < 4; r++)
            bias_v[mt][r] = ball[m0 + wm*64 + mt*16 + quad*4 + r];

    bf16* sEb = (bf16*)sE;
    if (my < 4) {
        #pragma unroll
        for (int mt = 0; mt < 4; mt++)
            #pragma unroll
            for (int nt = 0; nt < 4; nt++)
                #pragma unroll
                for (int r = 0; r < 4; r++)
                    sEb[(wn*64 + nt*16 + col)*136 + wm*64 + mt*16 + quad*4 + r] =
                        __float2bfloat16(acc[mt][nt][r] + bias_v[mt][r]);
        __syncthreads();
        bf16* dst = (my < 2) ? qT : kT;
        const int c0 = (my & 1) * 128;
        #pragma unroll
        for (int j = 0; j < 8; j++) {
            int idx = j*256 + t;
            int n = idx >> 4, c8 = (idx & 15) << 3;
            *(v8s*)(dst + (size_t)(n0 + n) * C + c0 + c8) = *(const v8s*)&sE[n*136 + c8];
        }
    } else {
        #pragma unroll
        for (int mt = 0; mt < 4; mt++)
            #pragma unroll
            for (int nt = 0; nt < 4; nt++)
                #pragma unroll
                for (int r = 0; r < 4; r++)
                    sEb[(wm*64 + mt*16 + quad*4 + r)*136 + wn*64 + nt*16 + col] =
                        __float2bfloat16(acc[mt][nt][r] + bias_v[mt][r]);
        __syncthreads();
        const int c0 = (my - 4) * 128;
        #pragma unroll
        for (int j = 0; j < 8; j++) {
            int idx = j*256 + t;
            int m = idx >> 4, n8 = (idx & 15) << 3;
            *(v8s*)(vB + (size_t)(c0 + m) * L + n0 + n8) = *(const v8s*)&sE[m*136 + n8];
        }
    }
}

// ---------------------------------------------------------------------------
// Output GEMM: out[512][L] = Wob[512][256].aoT[L][256]^T + bo, * mask.
// ---------------------------------------------------------------------------
__global__ __launch_bounds__(256) void out_gemm(
    const bf16* __restrict__ A, const bf16* __restrict__ B,
    const float* __restrict__ bo, const float* __restrict__ mask,
    float* __restrict__ out)
{
    __shared__ short sA[128*32];
    __shared__ short sB[128*32];
    __shared__ float sEf[64*132];

    const int t    = threadIdx.x;
    const int lane = t & 63;
    const int w    = t >> 6;
    const int wm   = w & 1, wn = w >> 1;
    const int col  = lane & 15, quad = lane >> 4;
    const int n0   = blockIdx.x * 128;
    const int m0   = blockIdx.y * 128;

    v4f acc[4][4];
    #pragma unroll
    for (int i = 0; i < 4; i++)
        #pragma unroll
        for (int j = 0; j < 4; j++) acc[i][j] = (v4f){0.f,0.f,0.f,0.f};

    for (int k0 = 0; k0 < C; k0 += 32) {
        #pragma unroll
        for (int j = 0; j < 2; j++) {
            int idx = j*256 + t;
            int m = idx >> 2, k8 = (idx & 3) << 3;
            ldst16(&sA[idx*8], A + (size_t)(m0 + m) * C + k0 + k8);
        }
        #pragma unroll
        for (int j = 0; j < 2; j++) {
            int idx = j*256 + t;
            int n = idx >> 2, k8 = (idx & 3) << 3;
            ldst16(&sB[idx*8], B + (size_t)(n0 + n) * C + k0 + k8);
        }
        __syncthreads();
        v8s af[4], bf[4];
        #pragma unroll
        for (int mt = 0; mt < 4; mt++)
            af[mt] = *(const v8s*)&sA[(wm*64 + mt*16 + col)*32 + quad*8];
        #pragma unroll
        for (int nt = 0; nt < 4; nt++)
            bf[nt] = *(const v8s*)&sB[(wn*64 + nt*16 + col)*32 + quad*8];
        #pragma unroll
        for (int mt = 0; mt < 4; mt++)
            #pragma unroll
            for (int nt = 0; nt < 4; nt++)
                acc[mt][nt] = __builtin_amdgcn_mfma_f32_16x16x32_bf16(af[mt], bf[nt], acc[mt][nt], 0, 0, 0);
        __syncthreads();
    }

    #pragma unroll
    for (int half = 0; half < 2; half++) {
        if (wm == half) {
            #pragma unroll
            for (int mt = 0; mt < 4; mt++) {
                #pragma unroll
                for (int r = 0; r < 4; r++) {
                    float bb = bo[m0 + half*64 + mt*16 + quad*4 + r];
                    #pragma unroll
                    for (int nt = 0; nt < 4; nt++)
                        sEf[(mt*16 + quad*4 + r)*132 + wn*64 + nt*16 + col] =
                            acc[mt][nt][r] + bb;
                }
            }
        }
        __syncthreads();
        #pragma unroll
        for (int j = 0; j < 8; j++) {
            int idx = j*256 + t;
            int row = idx >> 5, s4 = (idx & 31) << 2;
            float4 vv = *(const float4*)&sEf[row*132 + s4];
            float4 mk = *(const float4*)&mask[n0 + s4];
            vv.x *= mk.x; vv.y *= mk.y; vv.z *= mk.z; vv.w *= mk.w;
            *(float4*)&out[(size_t)(m0 + half*64 + row) * L + n0 + s4] = vv;
        }
        __syncthreads();
    }
}

// ---------------------------------------------------------------------------
// Flash sliding-window attention v3: barrier-free, global-direct fragments.
// 256 threads = 4 waves x 16 queries = 64 q/block, 512 blocks (XCD swizzle).
// K B-frags and V A-frags loaded straight from global (16 B/lane, one 64-B
// line per row); OOB addresses clamped (surrounding ws is mapped, values
// masked out downstream). LDS = wave-private P buffer only (9.2 KB).
// ---------------------------------------------------------------------------
__global__ __launch_bounds__(256, 3) void attn_mfma(
    const bf16* __restrict__ qT, const bf16* __restrict__ kT,
    const bf16* __restrict__ vB, const float* __restrict__ mask,
    bf16* __restrict__ aoT)
{
    __shared__ short sP[4][16*72];  // per-wave P [q][key], 9.2 KB total

    const int t    = threadIdx.x;
    const int w    = t >> 6;
    const int lane = t & 63;
    const int col  = lane & 15;
    const int quad = lane >> 4;
    const int bx   = blockIdx.x;
    const int tile = ((bx & 7) << 6) | (bx >> 3);   // XCD-contiguous p ranges
    const int p0   = tile * 64;
    const int abase = p0 - 256;

    // Q fragments (A-operand), loaded once
    v8s qf[8];
    {
        const short* qp = (const short*)qT + (size_t)(p0 + w*16 + col) * C + quad*8;
        #pragma unroll
        for (int ks = 0; ks < 8; ks++) qf[ks] = *(const v8s*)(qp + ks*32);
    }

    v4f oacc[16];
    #pragma unroll
    for (int i = 0; i < 16; i++) oacc[i] = (v4f){0.f, 0.f, 0.f, 0.f};
    float mrow[4] = {-1e30f, -1e30f, -1e30f, -1e30f};
    float lrow[4] = {0.f, 0.f, 0.f, 0.f};

    const short* kTs = (const short*)kT;
    const short* vBs = (const short*)vB;
    bf16* sPw  = (bf16*)sP[w];
    const short* sPws = (const short*)sP[w];

    for (int ch = 0; ch < 9; ch++) {
        const int a0 = abase + ch*64;

        // ---- QK^T: B-frags direct from global kT rows (clamped) ----
        v4f e[4];
        #pragma unroll
        for (int nt = 0; nt < 4; nt++) {
            int a  = a0 + nt*16 + col;
            int ac = min(max(a, 0), L - 1);
            const short* kp = kTs + (size_t)ac * C + quad*8;
            v4f acc = {0.f, 0.f, 0.f, 0.f};
            #pragma unroll
            for (int ks = 0; ks < 8; ks++) {
                v8s bfrag = *(const v8s*)(kp + ks*32);
                acc = __builtin_amdgcn_mfma_f32_16x16x32_bf16(qf[ks], bfrag, acc, 0, 0, 0);
            }
            e[nt] = acc;
        }

        // ---- mask + scale + row max ----
        float cmax[4] = {-1e30f, -1e30f, -1e30f, -1e30f};
        #pragma unroll
        for (int nt = 0; nt < 4; nt++) {
            int a  = a0 + nt*16 + col;
            int aa = ch*64 + nt*16 + col;
            float mval = (a >= 0 && a < L) ? mask[a] : 0.f;
            #pragma unroll
            for (int r = 0; r < 4; r++) {
                int rel = aa - (w*16 + quad*4 + r);
                bool valid = ((unsigned)rel < 512u) && (mval > 0.f);
                float ev = valid ? e[nt][r] * SCALE : -1e30f;
                e[nt][r] = ev;
                cmax[r] = fmaxf(cmax[r], ev);
            }
        }
        #pragma unroll
        for (int off = 1; off < 16; off <<= 1) {
            #pragma unroll
            for (int r = 0; r < 4; r++)
                cmax[r] = fmaxf(cmax[r], __shfl_xor(cmax[r], off));
        }

        float alpha[4];
        #pragma unroll
        for (int r = 0; r < 4; r++) {
            float mnew = fmaxf(mrow[r], cmax[r]);
            alpha[r] = __expf(mrow[r] - mnew);
            mrow[r] = mnew;
        }

        // ---- P = exp(E - m), row sums, P -> wave-private LDS ----
        float psum[4] = {0.f, 0.f, 0.f, 0.f};
        #pragma unroll
        for (int nt = 0; nt < 4; nt++) {
            #pragma unroll
            for (int r = 0; r < 4; r++) {
                float ev = e[nt][r];
                float p = (ev > -9e29f) ? __expf(ev - mrow[r]) : 0.f;
                psum[r] += p;
                sPw[(quad*4 + r)*72 + nt*16 + col] = __float2bfloat16(p);
            }
        }
        #pragma unroll
        for (int off = 1; off < 16; off <<= 1) {
            #pragma unroll
            for (int r = 0; r < 4; r++)
                psum[r] += __shfl_xor(psum[r], off);
        }
        #pragma unroll
        for (int r = 0; r < 4; r++) lrow[r] = lrow[r]*alpha[r] + psum[r];

        // ---- rescale O by alpha (broadcast to C-layout lanes) ----
        {
            int src = (col >> 2) << 4;
            float a0b = __shfl(alpha[0], src);
            float a1b = __shfl(alpha[1], src);
            float a2b = __shfl(alpha[2], src);
            float a3b = __shfl(alpha[3], src);
            int rr = col & 3;
            float aO = (rr == 0) ? a0b : (rr == 1) ? a1b : (rr == 2) ? a2b : a3b;
            #pragma unroll
            for (int i = 0; i < 16; i++) {
                oacc[i][0] *= aO; oacc[i][1] *= aO;
                oacc[i][2] *= aO; oacc[i][3] *= aO;
            }
        }

        // ---- PV: V A-frags direct from global vB rows (group-clamped) ----
        {
            v8s pf0 = *(const v8s*)&sPws[col*72 + quad*8];
            v8s pf1 = *(const v8s*)&sPws[col*72 + quad*8 + 32];
            int ag0 = a0 + quad*8;
            int ag1 = a0 + 32 + quad*8;
            int ac0 = min(max(ag0, 0), L - 8);
            int ac1 = min(max(ag1, 0), L - 8);
            #pragma unroll
            for (int ct = 0; ct < 16; ct++) {
                const short* vrow = vBs + (size_t)(ct*16 + col) * L;
                v8s vf0 = *(const v8s*)(vrow + ac0);
                v8s vf1 = *(const v8s*)(vrow + ac1);
                oacc[ct] = __builtin_amdgcn_mfma_f32_16x16x32_bf16(vf0, pf0, oacc[ct], 0, 0, 0);
                oacc[ct] = __builtin_amdgcn_mfma_f32_16x16x32_bf16(vf1, pf1, oacc[ct], 0, 0, 0);
            }
        }
    }

    // ---- epilogue: normalize, ReLU, bf16 store [l][c] ----
    {
        int src = (col >> 2) << 4;
        float l0b = __shfl(lrow[0], src);
        float l1b = __shfl(lrow[1], src);
        float l2b = __shfl(lrow[2], src);
        float l3b = __shfl(lrow[3], src);
        int rr = col & 3;
        float lO = (rr == 0) ? l0b : (rr == 1) ? l1b : (rr == 2) ? l2b : l3b;
        float inv = (lO > 0.f) ? 1.f / lO : 0.f;
        const int qg = p0 + w*16 + col;
        short* aorow = (short*)aoT + (size_t)qg * C;
        #pragma unroll
        for (int ct = 0; ct < 16; ct++) {
            v4s pk;
            #pragma unroll
            for (int r = 0; r < 4; r++)
                pk[r] = bfbits(fmaxf(oacc[ct][r] * inv, 0.f));
            *(v4s*)(aorow + ct*16 + quad*4) = pk;
        }
    }
}

extern "C" void kernel_launch(void* const* d_in, const int* in_sizes, int n_in,
                              void* d_out, int out_size, void* d_ws, size_t ws_size,
                              hipStream_t stream)
{
    const float* x1   = (const float*)d_in[0];
    const float* mask = (const float*)d_in[2];
    const float* Wq   = (const float*)d_in[3];
    const float* bq   = (const float*)d_in[4];
    const float* Wk   = (const float*)d_in[5];
    const float* bk   = (const float*)d_in[6];
    const float* Wv   = (const float*)d_in[7];
    const float* bv   = (const float*)d_in[8];
    const float* Wo   = (const float*)d_in[9];
    const float* bo   = (const float*)d_in[10];
    float* out = (float*)d_out;

    bf16* x1T  = (bf16*)d_ws;
    bf16* Wall = x1T + (size_t)L * QD;
    bf16* Wob  = Wall + 768*512;
    float* ball = (float*)(Wob + 512*256);
    bf16* qT   = (bf16*)(ball + 768);
    bf16* kT   = qT + (size_t)L * C;
    bf16* vB   = kT + (size_t)L * C;
    bf16* aoT  = vB + (size_t)L * C;

    dim3 blk(256);
    prep<<<dim3((768*512 + 512*256 + 768 + 255)/256), blk, 0, stream>>>(
        Wq, Wk, Wv, bq, bk, bv, Wo, Wall, Wob, ball);
    convt<<<dim3(L/64, QD/64), blk, 0, stream>>>(x1, (short*)x1T);
    qkv_gemm<<<dim3(L/128, 6), blk, 0, stream>>>(Wall, x1T, ball, qT, kT, vB);
    attn_mfma<<<dim3(L/64), blk, 0, stream>>>(qT, kT, vB, mask, aoT);
    out_gemm<<<dim3(L/128, 4), blk, 0, stream>>>(Wob, aoT, bo, mask, out);
}

// Round 6
// 290.940 us; speedup vs baseline: 1.4142x; 1.4142x over previous
//
#include <hip/hip_runtime.h>
#include <hip/hip_bf16.h>
#include <math.h>

#define L 32768
#define C 256
#define QD 512
#define SCALE (1.0f/16.0f)

typedef __hip_bfloat16 bf16;
typedef short v8s __attribute__((ext_vector_type(8)));
typedef short v4s __attribute__((ext_vector_type(4)));
typedef float v4f __attribute__((ext_vector_type(4)));

__device__ __forceinline__ void ldst16(void* lds, const void* g) {
    __builtin_amdgcn_global_load_lds(
        (const __attribute__((address_space(1))) unsigned int*)g,
        (__attribute__((address_space(3))) unsigned int*)lds, 16, 0, 0);
}
__device__ __forceinline__ short bfbits(float x) {
    bf16 h = __float2bfloat16(x);
    return *reinterpret_cast<short*>(&h);
}

// ---------------------------------------------------------------------------
// prep: pack Wq/Wk/Wv -> Wall bf16 [768][512]; Wo -> Wob bf16 [512][256];
// biases -> ball fp32 [768].
// ---------------------------------------------------------------------------
__global__ __launch_bounds__(256) void prep(
    const float* __restrict__ Wq, const float* __restrict__ Wk,
    const float* __restrict__ Wv, const float* __restrict__ bq,
    const float* __restrict__ bk, const float* __restrict__ bv,
    const float* __restrict__ Wo,
    bf16* __restrict__ Wall, bf16* __restrict__ Wob, float* __restrict__ ball)
{
    int i = blockIdx.x * 256 + threadIdx.x;
    if (i < 768*512) {
        int row = i >> 9, idx = i & 511;
        const float* src = row < 256 ? Wq : row < 512 ? Wk : Wv;
        Wall[i] = __float2bfloat16(src[(row & 255) * 512 + idx]);
    } else if (i < 768*512 + 512*256) {
        int j = i - 768*512;
        Wob[j] = __float2bfloat16(Wo[j]);
    } else if (i < 768*512 + 512*256 + 768) {
        int j = i - 768*512 - 512*256;
        ball[j] = j < 256 ? bq[j] : j < 512 ? bk[j - 256] : bv[j - 512];
    }
}

// ---------------------------------------------------------------------------
// convt: x1 fp32 [512][L] -> x1T bf16 [L][512], 64x64 tiles via LDS.
// ---------------------------------------------------------------------------
__global__ __launch_bounds__(256) void convt(
    const float* __restrict__ x, short* __restrict__ xT)
{
    __shared__ short st[64*72];
    const int t = threadIdx.x;
    const int l0 = blockIdx.x * 64, c0 = blockIdx.y * 64;
    #pragma unroll
    for (int i = 0; i < 2; i++) {
        int v = i*256 + t;
        int c = v >> 3, l8 = (v & 7) << 3;
        const float* p = x + (size_t)(c0 + c) * L + l0 + l8;
        float4 f0 = *(const float4*)p;
        float4 f1 = *(const float4*)(p + 4);
        bf16* stb = (bf16*)st;
        stb[(l8+0)*72 + c] = __float2bfloat16(f0.x);
        stb[(l8+1)*72 + c] = __float2bfloat16(f0.y);
        stb[(l8+2)*72 + c] = __float2bfloat16(f0.z);
        stb[(l8+3)*72 + c] = __float2bfloat16(f0.w);
        stb[(l8+4)*72 + c] = __float2bfloat16(f1.x);
        stb[(l8+5)*72 + c] = __float2bfloat16(f1.y);
        stb[(l8+6)*72 + c] = __float2bfloat16(f1.z);
        stb[(l8+7)*72 + c] = __float2bfloat16(f1.w);
    }
    __syncthreads();
    #pragma unroll
    for (int i = 0; i < 2; i++) {
        int v = i*256 + t;
        int l = v >> 3, c8 = (v & 7) << 3;
        *(v8s*)(xT + (size_t)(l0 + l) * QD + c0 + c8) = *(const v8s*)&st[l*72 + c8];
    }
}

// ---------------------------------------------------------------------------
// Fused QKV GEMM (m97-style): Y[768][L] = Wall[768][512] . x1T[L][512]^T.
// ---------------------------------------------------------------------------
__global__ __launch_bounds__(256) void qkv_gemm(
    const bf16* __restrict__ A, const bf16* __restrict__ B,
    const float* __restrict__ ball,
    bf16* __restrict__ qT, bf16* __restrict__ kT, bf16* __restrict__ vB)
{
    __shared__ short sA[128*32];
    __shared__ short sB[128*32];
    __shared__ short sE[128*136];

    const int t    = threadIdx.x;
    const int lane = t & 63;
    const int w    = t >> 6;
    const int wm   = w & 1, wn = w >> 1;
    const int col  = lane & 15, quad = lane >> 4;
    const int n0   = blockIdx.x * 128;
    const int my   = blockIdx.y;
    const int m0   = my * 128;

    v4f acc[4][4];
    #pragma unroll
    for (int i = 0; i < 4; i++)
        #pragma unroll
        for (int j = 0; j < 4; j++) acc[i][j] = (v4f){0.f,0.f,0.f,0.f};

    for (int k0 = 0; k0 < QD; k0 += 32) {
        #pragma unroll
        for (int j = 0; j < 2; j++) {
            int idx = j*256 + t;
            int m = idx >> 2, k8 = (idx & 3) << 3;
            ldst16(&sA[idx*8], A + (size_t)(m0 + m) * QD + k0 + k8);
        }
        #pragma unroll
        for (int j = 0; j < 2; j++) {
            int idx = j*256 + t;
            int n = idx >> 2, k8 = (idx & 3) << 3;
            ldst16(&sB[idx*8], B + (size_t)(n0 + n) * QD + k0 + k8);
        }
        __syncthreads();
        v8s af[4], bf[4];
        #pragma unroll
        for (int mt = 0; mt < 4; mt++)
            af[mt] = *(const v8s*)&sA[(wm*64 + mt*16 + col)*32 + quad*8];
        #pragma unroll
        for (int nt = 0; nt < 4; nt++)
            bf[nt] = *(const v8s*)&sB[(wn*64 + nt*16 + col)*32 + quad*8];
        #pragma unroll
        for (int mt = 0; mt < 4; mt++)
            #pragma unroll
            for (int nt = 0; nt < 4; nt++)
                acc[mt][nt] = __builtin_amdgcn_mfma_f32_16x16x32_bf16(af[mt], bf[nt], acc[mt][nt], 0, 0, 0);
        __syncthreads();
    }

    float bias_v[4][4];
    #pragma unroll
    for (int mt = 0; mt < 4; mt++)
        #pragma unroll
        for (int r = 0; r < 4; r++)
            bias_v[mt][r] = ball[m0 + wm*64 + mt*16 + quad*4 + r];

    bf16* sEb = (bf16*)sE;
    if (my < 4) {
        #pragma unroll
        for (int mt = 0; mt < 4; mt++)
            #pragma unroll
            for (int nt = 0; nt < 4; nt++)
                #pragma unroll
                for (int r = 0; r < 4; r++)
                    sEb[(wn*64 + nt*16 + col)*136 + wm*64 + mt*16 + quad*4 + r] =
                        __float2bfloat16(acc[mt][nt][r] + bias_v[mt][r]);
        __syncthreads();
        bf16* dst = (my < 2) ? qT : kT;
        const int c0 = (my & 1) * 128;
        #pragma unroll
        for (int j = 0; j < 8; j++) {
            int idx = j*256 + t;
            int n = idx >> 4, c8 = (idx & 15) << 3;
            *(v8s*)(dst + (size_t)(n0 + n) * C + c0 + c8) = *(const v8s*)&sE[n*136 + c8];
        }
    } else {
        #pragma unroll
        for (int mt = 0; mt < 4; mt++)
            #pragma unroll
            for (int nt = 0; nt < 4; nt++)
                #pragma unroll
                for (int r = 0; r < 4; r++)
                    sEb[(wm*64 + mt*16 + quad*4 + r)*136 + wn*64 + nt*16 + col] =
                        __float2bfloat16(acc[mt][nt][r] + bias_v[mt][r]);
        __syncthreads();
        const int c0 = (my - 4) * 128;
        #pragma unroll
        for (int j = 0; j < 8; j++) {
            int idx = j*256 + t;
            int m = idx >> 4, n8 = (idx & 15) << 3;
            *(v8s*)(vB + (size_t)(c0 + m) * L + n0 + n8) = *(const v8s*)&sE[m*136 + n8];
        }
    }
}

// ---------------------------------------------------------------------------
// Output GEMM: out[512][L] = Wob[512][256].aoT[L][256]^T + bo, * mask.
// ---------------------------------------------------------------------------
__global__ __launch_bounds__(256) void out_gemm(
    const bf16* __restrict__ A, const bf16* __restrict__ B,
    const float* __restrict__ bo, const float* __restrict__ mask,
    float* __restrict__ out)
{
    __shared__ short sA[128*32];
    __shared__ short sB[128*32];
    __shared__ float sEf[64*132];

    const int t    = threadIdx.x;
    const int lane = t & 63;
    const int w    = t >> 6;
    const int wm   = w & 1, wn = w >> 1;
    const int col  = lane & 15, quad = lane >> 4;
    const int n0   = blockIdx.x * 128;
    const int m0   = blockIdx.y * 128;

    v4f acc[4][4];
    #pragma unroll
    for (int i = 0; i < 4; i++)
        #pragma unroll
        for (int j = 0; j < 4; j++) acc[i][j] = (v4f){0.f,0.f,0.f,0.f};

    for (int k0 = 0; k0 < C; k0 += 32) {
        #pragma unroll
        for (int j = 0; j < 2; j++) {
            int idx = j*256 + t;
            int m = idx >> 2, k8 = (idx & 3) << 3;
            ldst16(&sA[idx*8], A + (size_t)(m0 + m) * C + k0 + k8);
        }
        #pragma unroll
        for (int j = 0; j < 2; j++) {
            int idx = j*256 + t;
            int n = idx >> 2, k8 = (idx & 3) << 3;
            ldst16(&sB[idx*8], B + (size_t)(n0 + n) * C + k0 + k8);
        }
        __syncthreads();
        v8s af[4], bf[4];
        #pragma unroll
        for (int mt = 0; mt < 4; mt++)
            af[mt] = *(const v8s*)&sA[(wm*64 + mt*16 + col)*32 + quad*8];
        #pragma unroll
        for (int nt = 0; nt < 4; nt++)
            bf[nt] = *(const v8s*)&sB[(wn*64 + nt*16 + col)*32 + quad*8];
        #pragma unroll
        for (int mt = 0; mt < 4; mt++)
            #pragma unroll
            for (int nt = 0; nt < 4; nt++)
                acc[mt][nt] = __builtin_amdgcn_mfma_f32_16x16x32_bf16(af[mt], bf[nt], acc[mt][nt], 0, 0, 0);
        __syncthreads();
    }

    #pragma unroll
    for (int half = 0; half < 2; half++) {
        if (wm == half) {
            #pragma unroll
            for (int mt = 0; mt < 4; mt++) {
                #pragma unroll
                for (int r = 0; r < 4; r++) {
                    float bb = bo[m0 + half*64 + mt*16 + quad*4 + r];
                    #pragma unroll
                    for (int nt = 0; nt < 4; nt++)
                        sEf[(mt*16 + quad*4 + r)*132 + wn*64 + nt*16 + col] =
                            acc[mt][nt][r] + bb;
                }
            }
        }
        __syncthreads();
        #pragma unroll
        for (int j = 0; j < 8; j++) {
            int idx = j*256 + t;
            int row = idx >> 5, s4 = (idx & 31) << 2;
            float4 vv = *(const float4*)&sEf[row*132 + s4];
            float4 mk = *(const float4*)&mask[n0 + s4];
            vv.x *= mk.x; vv.y *= mk.y; vv.z *= mk.z; vv.w *= mk.w;
            *(float4*)&out[(size_t)(m0 + half*64 + row) * L + n0 + s4] = vv;
        }
        __syncthreads();
    }
}

// ---------------------------------------------------------------------------
// Flash sliding-window attention v4: 128 q/block, 512 threads (8 waves x 16q),
// LDS double-buffered K/V (one barrier per chunk), register-relay prefetch,
// clamped branch-free edge loads, XCD-swizzled p-tiles.
// LDS: 2*(33.8+36.9) + 18.4 = 156 KB -> 1 block/CU.
// ---------------------------------------------------------------------------
__device__ __forceinline__ void load_chunk(
    const short* __restrict__ kT, const short* __restrict__ vB,
    int a0, int t, v8s kreg[4], v8s vreg[4])
{
    // chunks are 64-aligned: either fully inside [0,L) or fully outside,
    // so clamping never mixes valid/invalid within a row. Clamped rows are
    // finite duplicates and are killed by the mask logic downstream.
    #pragma unroll
    for (int j = 0; j < 4; j++) {
        int idx = j*512 + t;
        int r = idx >> 5, s = idx & 31;
        int a = min(max(a0 + r, 0), L - 1);
        kreg[j] = *(const v8s*)(kT + (size_t)a * C + s*8);
    }
    #pragma unroll
    for (int j = 0; j < 4; j++) {
        int idx = j*512 + t;
        int c = idx >> 3, s = idx & 7;
        int ab = min(max(a0 + s*8, 0), L - 8);
        vreg[j] = *(const v8s*)(vB + (size_t)c * L + ab);
    }
}

__device__ __forceinline__ void store_chunk(
    short* __restrict__ sK, short* __restrict__ sVt, int t,
    const v8s kreg[4], const v8s vreg[4])
{
    #pragma unroll
    for (int j = 0; j < 4; j++) {
        int idx = j*512 + t;
        int r = idx >> 5, s = idx & 31;
        *(v8s*)&sK[r*264 + s*8] = kreg[j];
    }
    #pragma unroll
    for (int j = 0; j < 4; j++) {
        int idx = j*512 + t;
        int c = idx >> 3, s = idx & 7;
        *(v8s*)&sVt[c*72 + s*8] = vreg[j];
    }
}

__global__ __launch_bounds__(512, 1) void attn_mfma(
    const bf16* __restrict__ qT, const bf16* __restrict__ kT,
    const bf16* __restrict__ vB, const float* __restrict__ mask,
    bf16* __restrict__ aoT)
{
    __shared__ short sK [2][64*264];   // 2 x 33.8 KB
    __shared__ short sVt[2][256*72];   // 2 x 36.9 KB
    __shared__ short sP [8][16*72];    // 18.4 KB

    const int t    = threadIdx.x;
    const int w    = t >> 6;
    const int lane = t & 63;
    const int col  = lane & 15;
    const int quad = lane >> 4;
    const int bx   = blockIdx.x;
    const int tile = ((bx & 7) << 5) | (bx >> 3);   // XCD-contiguous p ranges
    const int p0   = tile * 128;
    const int abase = p0 - 256;

    v8s qf[8];
    {
        const short* qp = (const short*)qT + (size_t)(p0 + w*16 + col) * C + quad*8;
        #pragma unroll
        for (int ks = 0; ks < 8; ks++) qf[ks] = *(const v8s*)(qp + ks*32);
    }

    v4f oacc[16];
    #pragma unroll
    for (int i = 0; i < 16; i++) oacc[i] = (v4f){0.f, 0.f, 0.f, 0.f};
    float mrow[4] = {-1e30f, -1e30f, -1e30f, -1e30f};
    float lrow[4] = {0.f, 0.f, 0.f, 0.f};

    const short* kTs = (const short*)kT;
    const short* vBs = (const short*)vB;
    bf16* sPw  = (bf16*)sP[w];
    const short* sPws = (const short*)sP[w];

    v8s kreg[4], vreg[4];
    load_chunk(kTs, vBs, abase, t, kreg, vreg);
    store_chunk(sK[0], sVt[0], t, kreg, vreg);
    __syncthreads();

    for (int ch = 0; ch < 10; ch++) {
        const int a0  = abase + ch*64;
        const int cur = ch & 1;
        const bool pf = (ch < 9);
        if (pf)
            load_chunk(kTs, vBs, a0 + 64, t, kreg, vreg);

        // ---- QK^T from sK[cur] ----
        v4f e[4];
        #pragma unroll
        for (int nt = 0; nt < 4; nt++) {
            v4f acc = {0.f, 0.f, 0.f, 0.f};
            const short* kp = &sK[cur][(nt*16 + col)*264 + quad*8];
            #pragma unroll
            for (int ks = 0; ks < 8; ks++) {
                v8s bfrag = *(const v8s*)(kp + ks*32);
                acc = __builtin_amdgcn_mfma_f32_16x16x32_bf16(qf[ks], bfrag, acc, 0, 0, 0);
            }
            e[nt] = acc;
        }

        // ---- mask + scale + row max ----
        float cmax[4] = {-1e30f, -1e30f, -1e30f, -1e30f};
        #pragma unroll
        for (int nt = 0; nt < 4; nt++) {
            int a  = a0 + nt*16 + col;
            int aa = ch*64 + nt*16 + col;
            float mval = (a >= 0 && a < L) ? mask[a] : 0.f;
            #pragma unroll
            for (int r = 0; r < 4; r++) {
                int rel = aa - (w*16 + quad*4 + r);
                bool valid = ((unsigned)rel < 512u) && (mval > 0.f);
                float ev = valid ? e[nt][r] * SCALE : -1e30f;
                e[nt][r] = ev;
                cmax[r] = fmaxf(cmax[r], ev);
            }
        }
        #pragma unroll
        for (int off = 1; off < 16; off <<= 1) {
            #pragma unroll
            for (int r = 0; r < 4; r++)
                cmax[r] = fmaxf(cmax[r], __shfl_xor(cmax[r], off));
        }

        float alpha[4];
        #pragma unroll
        for (int r = 0; r < 4; r++) {
            float mnew = fmaxf(mrow[r], cmax[r]);
            alpha[r] = __expf(mrow[r] - mnew);
            mrow[r] = mnew;
        }

        // ---- P = exp(E - m), row sums, P -> wave-private LDS ----
        float psum[4] = {0.f, 0.f, 0.f, 0.f};
        #pragma unroll
        for (int nt = 0; nt < 4; nt++) {
            #pragma unroll
            for (int r = 0; r < 4; r++) {
                float ev = e[nt][r];
                float p = (ev > -9e29f) ? __expf(ev - mrow[r]) : 0.f;
                psum[r] += p;
                sPw[(quad*4 + r)*72 + nt*16 + col] = __float2bfloat16(p);
            }
        }
        #pragma unroll
        for (int off = 1; off < 16; off <<= 1) {
            #pragma unroll
            for (int r = 0; r < 4; r++)
                psum[r] += __shfl_xor(psum[r], off);
        }
        #pragma unroll
        for (int r = 0; r < 4; r++) lrow[r] = lrow[r]*alpha[r] + psum[r];

        // ---- rescale O ----
        {
            int src = (col >> 2) << 4;
            float a0b = __shfl(alpha[0], src);
            float a1b = __shfl(alpha[1], src);
            float a2b = __shfl(alpha[2], src);
            float a3b = __shfl(alpha[3], src);
            int rr = col & 3;
            float aO = (rr == 0) ? a0b : (rr == 1) ? a1b : (rr == 2) ? a2b : a3b;
            #pragma unroll
            for (int i = 0; i < 16; i++) {
                oacc[i][0] *= aO; oacc[i][1] *= aO;
                oacc[i][2] *= aO; oacc[i][3] *= aO;
            }
        }

        // ---- PV from sVt[cur] ----
        {
            v8s pf0 = *(const v8s*)&sPws[col*72 + quad*8];
            v8s pf1 = *(const v8s*)&sPws[col*72 + quad*8 + 32];
            #pragma unroll
            for (int ct = 0; ct < 16; ct++) {
                const short* vp = &sVt[cur][(ct*16 + col)*72 + quad*8];
                v8s vf0 = *(const v8s*)vp;
                v8s vf1 = *(const v8s*)(vp + 32);
                oacc[ct] = __builtin_amdgcn_mfma_f32_16x16x32_bf16(vf0, pf0, oacc[ct], 0, 0, 0);
                oacc[ct] = __builtin_amdgcn_mfma_f32_16x16x32_bf16(vf1, pf1, oacc[ct], 0, 0, 0);
            }
        }

        // ---- store prefetched chunk into the other buffer, one barrier ----
        if (pf) {
            store_chunk(sK[cur ^ 1], sVt[cur ^ 1], t, kreg, vreg);
            __syncthreads();
        }
    }

    // ---- epilogue ----
    {
        int src = (col >> 2) << 4;
        float l0b = __shfl(lrow[0], src);
        float l1b = __shfl(lrow[1], src);
        float l2b = __shfl(lrow[2], src);
        float l3b = __shfl(lrow[3], src);
        int rr = col & 3;
        float lO = (rr == 0) ? l0b : (rr == 1) ? l1b : (rr == 2) ? l2b : l3b;
        float inv = (lO > 0.f) ? 1.f / lO : 0.f;
        const int qg = p0 + w*16 + col;
        short* aorow = (short*)aoT + (size_t)qg * C;
        #pragma unroll
        for (int ct = 0; ct < 16; ct++) {
            v4s pk;
            #pragma unroll
            for (int r = 0; r < 4; r++)
                pk[r] = bfbits(fmaxf(oacc[ct][r] * inv, 0.f));
            *(v4s*)(aorow + ct*16 + quad*4) = pk;
        }
    }
}

extern "C" void kernel_launch(void* const* d_in, const int* in_sizes, int n_in,
                              void* d_out, int out_size, void* d_ws, size_t ws_size,
                              hipStream_t stream)
{
    const float* x1   = (const float*)d_in[0];
    const float* mask = (const float*)d_in[2];
    const float* Wq   = (const float*)d_in[3];
    const float* bq   = (const float*)d_in[4];
    const float* Wk   = (const float*)d_in[5];
    const float* bk   = (const float*)d_in[6];
    const float* Wv   = (const float*)d_in[7];
    const float* bv   = (const float*)d_in[8];
    const float* Wo   = (const float*)d_in[9];
    const float* bo   = (const float*)d_in[10];
    float* out = (float*)d_out;

    bf16* x1T  = (bf16*)d_ws;
    bf16* Wall = x1T + (size_t)L * QD;
    bf16* Wob  = Wall + 768*512;
    float* ball = (float*)(Wob + 512*256);
    bf16* qT   = (bf16*)(ball + 768);
    bf16* kT   = qT + (size_t)L * C;
    bf16* vB   = kT + (size_t)L * C;
    bf16* aoT  = vB + (size_t)L * C;

    dim3 blk(256);
    prep<<<dim3((768*512 + 512*256 + 768 + 255)/256), blk, 0, stream>>>(
        Wq, Wk, Wv, bq, bk, bv, Wo, Wall, Wob, ball);
    convt<<<dim3(L/64, QD/64), blk, 0, stream>>>(x1, (short*)x1T);
    qkv_gemm<<<dim3(L/128, 6), blk, 0, stream>>>(Wall, x1T, ball, qT, kT, vB);
    attn_mfma<<<dim3(L/128), dim3(512), 0, stream>>>(qT, kT, vB, mask, aoT);
    out_gemm<<<dim3(L/128, 4), blk, 0, stream>>>(Wob, aoT, bo, mask, out);
}